// Round 2
// baseline (703.847 us; speedup 1.0000x reference)
//
#include <hip/hip_runtime.h>

typedef __bf16 bf16_t;
typedef bf16_t bf16x8 __attribute__((ext_vector_type(8)));
typedef bf16_t bf16x4 __attribute__((ext_vector_type(4)));
typedef float f32x4 __attribute__((ext_vector_type(4)));
typedef unsigned int u32;

typedef __attribute__((address_space(1))) unsigned as1_u32;
typedef __attribute__((address_space(3))) unsigned as3_u32;

// async global->LDS, 16B per lane, LDS dest = wave-uniform base + lane*16
__device__ __forceinline__ void gload16(const void* g, void* l) {
  __builtin_amdgcn_global_load_lds((as1_u32*)(void*)g, (as3_u32*)l, 16, 0, 0);
}

// ---------------------------------------------------------------------------
// fp32 -> bf16 bulk convert. n multiple of 1024. grid n/1024, block 256.
__global__ void cvt_f32_bf16(const float* __restrict__ src,
                             bf16_t* __restrict__ dst, int n) {
  const int i = (blockIdx.x * 256 + threadIdx.x) * 4;
  if (i < n) {
    const float4 v = *(const float4*)(src + i);
    bf16x4 o;
    o[0] = (bf16_t)v.x; o[1] = (bf16_t)v.y; o[2] = (bf16_t)v.z; o[3] = (bf16_t)v.w;
    *(bf16x4*)(dst + i) = o;
  }
}

// ---------------------------------------------------------------------------
// Mask prep: detect bool-bytes vs int32, build additive float mask (0 / -1e4)
// with the reference's "all-pad row -> unmask last key" fix. grid 8, block 256.
__global__ void prep_mask(const unsigned char* __restrict__ mraw,
                          float* __restrict__ maskf) {
  __shared__ int sred[256];
  const int t = threadIdx.x, b = blockIdx.x;
  // int32 0/1 values have zero bytes at offsets %4!=0; bool-bytes don't.
  int f = 0;
  for (int i = t; i < 2048; i += 256) {
    u32 v = ((const u32*)mraw)[i];
    if (v & 0xFFFFFF00u) f = 1;
  }
  sred[t] = f; __syncthreads();
  for (int s = 128; s; s >>= 1) { if (t < s) sred[t] |= sred[t + s]; __syncthreads(); }
  const int isByte = sred[0];
  __syncthreads();

  int vals[4]; int allpad = 1;
#pragma unroll
  for (int i = 0; i < 4; i++) {
    int k = t * 4 + i;
    int mv = isByte ? (int)mraw[b * 1024 + k] : ((const int*)mraw)[b * 1024 + k];
    vals[i] = (mv != 0);
    allpad &= vals[i];
  }
  sred[t] = allpad; __syncthreads();
  for (int s = 128; s; s >>= 1) { if (t < s) sred[t] &= sred[t + s]; __syncthreads(); }
  const int ap = sred[0];
#pragma unroll
  for (int i = 0; i < 4; i++) {
    int k = t * 4 + i;
    int m = vals[i];
    if (ap && k == 1023) m = 0;
    maskf[b * 1024 + k] = m ? -10000.0f : 0.0f;
  }
}

// ---------------------------------------------------------------------------
// Weight transpose + downcast: W[K][N] fp32 -> WT[N][K] bf16.
// grid (N/64, K/64), block 256.
__global__ void transpose_w(const float* __restrict__ W, bf16_t* __restrict__ WT,
                            int K, int N) {
  __shared__ float tile[64][65];   // +1 pad: conflict-free column reads
  const int t = threadIdx.x;
  const int n0 = blockIdx.x * 64, k0 = blockIdx.y * 64;
#pragma unroll
  for (int i = 0; i < 16; i++) {
    int e = i * 256 + t; int r = e >> 6, c = e & 63;
    tile[r][c] = W[(size_t)(k0 + r) * N + n0 + c];
  }
  __syncthreads();
#pragma unroll
  for (int i = 0; i < 16; i++) {
    int e = i * 256 + t; int r = e >> 6, c = e & 63;
    WT[(size_t)(n0 + r) * K + k0 + c] = (bf16_t)tile[c][r];
  }
}

// ---------------------------------------------------------------------------
// GEMM: C[M][N] = A[M][K] @ BT[N][K]^T + bias (+optional relu), bf16 in/out,
// fp32 accum, fp32 bias. 128x128 tile, BK=32, 16x16x32 MFMA, global_load_lds.
// grid (N/128, M/128), block 256 (4 waves, each 64x64).
__global__ __launch_bounds__(256)
void gemm_bt(const bf16_t* __restrict__ A, const bf16_t* __restrict__ BT,
             const float* __restrict__ bias, bf16_t* __restrict__ C,
             int M, int N, int K, int relu) {
  __shared__ __align__(16) bf16_t As[128 * 32];
  __shared__ __align__(16) bf16_t Bs[128 * 32];
  const int tid = threadIdx.x;
  const int wave = tid >> 6, lane = tid & 63;
  const int quad = lane >> 4, l15 = lane & 15;
  const long bm = (long)blockIdx.y * 128, bn = (long)blockIdx.x * 128;
  const int wm = (wave >> 1) * 64, wn = (wave & 1) * 64;

  f32x4 acc[4][4];
#pragma unroll
  for (int i = 0; i < 4; i++)
#pragma unroll
    for (int j = 0; j < 4; j++) acc[i][j] = (f32x4){0.f, 0.f, 0.f, 0.f};

  // wave stages rows [wave*32, wave*32+32) of both tiles (2 insts of 16 rows)
  const bf16_t* ag = A + (bm + wave * 32 + (lane >> 2)) * (long)K + (lane & 3) * 8;
  const bf16_t* bg = BT + (bn + wave * 32 + (lane >> 2)) * (long)K + (lane & 3) * 8;
  bf16_t* as_dst = &As[wave * 1024];
  bf16_t* bs_dst = &Bs[wave * 1024];

  for (int k0 = 0; k0 < K; k0 += 32) {
    gload16(ag + k0, as_dst);
    gload16(ag + k0 + (long)16 * K, as_dst + 512);
    gload16(bg + k0, bs_dst);
    gload16(bg + k0 + (long)16 * K, bs_dst + 512);
    __syncthreads();   // drains vmcnt (global_load_lds) + lgkm

    bf16x8 af[4], bf[4];
#pragma unroll
    for (int i = 0; i < 4; i++)
      af[i] = *(const bf16x8*)&As[(wm + i * 16 + l15) * 32 + quad * 8];
#pragma unroll
    for (int i = 0; i < 4; i++)
      bf[i] = *(const bf16x8*)&Bs[(wn + i * 16 + l15) * 32 + quad * 8];
#pragma unroll
    for (int mi = 0; mi < 4; mi++)
#pragma unroll
      for (int ni = 0; ni < 4; ni++)
        acc[mi][ni] = __builtin_amdgcn_mfma_f32_16x16x32_bf16(af[mi], bf[ni], acc[mi][ni], 0, 0, 0);
    __syncthreads();
  }

  // epilogue: C/D layout col=lane&15, row=quad*4+reg (m89-verified)
#pragma unroll
  for (int mi = 0; mi < 4; mi++) {
#pragma unroll
    for (int ni = 0; ni < 4; ni++) {
      const long col = bn + wn + ni * 16 + l15;
      const float bv = bias[col];
#pragma unroll
      for (int r = 0; r < 4; r++) {
        const long row = bm + wm + mi * 16 + quad * 4 + r;
        float v = acc[mi][ni][r] + bv;
        if (relu) v = v > 0.f ? v : 0.f;
        C[row * N + col] = (bf16_t)v;
      }
    }
  }
}

// ---------------------------------------------------------------------------
// Flash attention. grid (Lq/64, H, B), block 256 (4 waves). Each wave owns 16
// q-rows of the 64-row Q tile. Q/K tiles XOR-swizzled on 16B blocks by (row&7)
// so b128 frag reads are conflict-free. P round-trips per-wave LDS (m120).
__global__ __launch_bounds__(256)
void attn(const bf16_t* __restrict__ Q, const bf16_t* __restrict__ Kp,
          const bf16_t* __restrict__ Vp, const float* __restrict__ maskf,
          bf16_t* __restrict__ AO) {
  __shared__ __align__(16) bf16_t Qs[64 * 64];
  __shared__ __align__(16) bf16_t Ks[64 * 64];
  __shared__ __align__(16) bf16_t Vs[64 * 64];
  __shared__ __align__(16) bf16_t Ps[4][16 * 64];
  __shared__ float msk[64];

  const int tid = threadIdx.x;
  const int wave = tid >> 6, lane = tid & 63;
  const int quad = lane >> 4, l15 = lane & 15;
  const int q0 = blockIdx.x * 64;
  const int h = blockIdx.y;
  const int b = blockIdx.z;

  const long base_q = ((long)b * 1024 + q0) * 1024 + h * 64;
  const long base_kv = (long)b * 1024 * 1024 + h * 64;

  // Q tile (swizzled): 512 16B chunks
#pragma unroll
  for (int i = 0; i < 2; i++) {
    int e = i * 256 + tid; int r = e >> 3, blk = e & 7;
    const int4 v = *(const int4*)(Q + base_q + (long)r * 1024 + blk * 8);
    *(int4*)&Qs[r * 64 + ((blk ^ (r & 7)) * 8)] = v;
  }

  float m_i[4], l_i[4];
  f32x4 o[4];
#pragma unroll
  for (int r = 0; r < 4; r++) { m_i[r] = -1e30f; l_i[r] = 0.f; }
#pragma unroll
  for (int nt = 0; nt < 4; nt++) o[nt] = (f32x4){0.f, 0.f, 0.f, 0.f};

  bf16_t* Pw = &Ps[wave][0];

  for (int kt = 0; kt < 16; kt++) {
    const int k0 = kt * 64;
    __syncthreads();   // prior-iter reads done (also covers Qs first use)
    // K tile (swizzled, via regs)
#pragma unroll
    for (int i = 0; i < 2; i++) {
      int e = i * 256 + tid; int r = e >> 3, blk = e & 7;
      const int4 v = *(const int4*)(Kp + base_kv + (long)(k0 + r) * 1024 + blk * 8);
      *(int4*)&Ks[r * 64 + ((blk ^ (r & 7)) * 8)] = v;
    }
    // V tile natural [ki][hd] via global_load_lds (rows are 128B contiguous)
    {
      const int j0 = wave * 2;
      const bf16_t* vg = Vp + base_kv + (long)(k0 + j0 * 8 + (lane >> 3)) * 1024 + (lane & 7) * 8;
      gload16(vg, &Vs[j0 * 512]);
      gload16(vg + (long)8 * 1024, &Vs[(j0 + 1) * 512]);
    }
    if (tid < 64) msk[tid] = maskf[b * 1024 + k0 + tid];
    __syncthreads();

    // S = Q K^T for this wave's 16 rows x 64 keys
    bf16x8 aq[2];
#pragma unroll
    for (int ks = 0; ks < 2; ks++) {
      int row = wave * 16 + l15;
      aq[ks] = *(const bf16x8*)&Qs[row * 64 + (((ks * 4 + quad) ^ (row & 7)) * 8)];
    }
    f32x4 sc[4];
#pragma unroll
    for (int nt = 0; nt < 4; nt++) {
      f32x4 s = (f32x4){0.f, 0.f, 0.f, 0.f};
#pragma unroll
      for (int ks = 0; ks < 2; ks++) {
        int krow = nt * 16 + l15;
        bf16x8 bk = *(const bf16x8*)&Ks[krow * 64 + (((ks * 4 + quad) ^ (krow & 7)) * 8)];
        s = __builtin_amdgcn_mfma_f32_16x16x32_bf16(aq[ks], bk, s, 0, 0, 0);
      }
      sc[nt] = s;
    }

    // online softmax (row = quad*4+r, col = nt*16+l15; stats across 16 lanes)
#pragma unroll
    for (int r = 0; r < 4; r++) {
      float mx = -1e30f;
#pragma unroll
      for (int nt = 0; nt < 4; nt++) {
        float mv = msk[nt * 16 + l15];
        float s = (mv < 0.f) ? -10000.f : sc[nt][r] * 0.125f;
        sc[nt][r] = s;
        mx = fmaxf(mx, s);
      }
      mx = fmaxf(mx, __shfl_xor(mx, 1));
      mx = fmaxf(mx, __shfl_xor(mx, 2));
      mx = fmaxf(mx, __shfl_xor(mx, 4));
      mx = fmaxf(mx, __shfl_xor(mx, 8));
      const float mnew = fmaxf(m_i[r], mx);
      const float alpha = __expf(m_i[r] - mnew);
      float ps = 0.f;
#pragma unroll
      for (int nt = 0; nt < 4; nt++) {
        float p = __expf(sc[nt][r] - mnew);
        sc[nt][r] = p;
        ps += p;
      }
      ps += __shfl_xor(ps, 1); ps += __shfl_xor(ps, 2);
      ps += __shfl_xor(ps, 4); ps += __shfl_xor(ps, 8);
      l_i[r] = l_i[r] * alpha + ps;
      m_i[r] = mnew;
#pragma unroll
      for (int nt = 0; nt < 4; nt++) o[nt][r] *= alpha;
    }

    // P (bf16) -> per-wave LDS, swizzled; same-wave read back (no barrier)
#pragma unroll
    for (int nt = 0; nt < 4; nt++)
#pragma unroll
      for (int r = 0; r < 4; r++) {
        int row = quad * 4 + r;
        int col = nt * 16 + l15;
        Pw[row * 64 + (((col >> 3) ^ (row & 7)) * 8) + (col & 7)] = (bf16_t)sc[nt][r];
      }

    // O += P V
#pragma unroll
    for (int ks = 0; ks < 2; ks++) {
      bf16x8 ap = *(const bf16x8*)&Pw[l15 * 64 + (((ks * 4 + quad) ^ (l15 & 7)) * 8)];
#pragma unroll
      for (int nt = 0; nt < 4; nt++) {
        bf16x8 bv;
        const int hd = nt * 16 + l15;
        const int kb = ks * 32 + quad * 8;
#pragma unroll
        for (int j = 0; j < 8; j++) bv[j] = Vs[(kb + j) * 64 + hd];
        o[nt] = __builtin_amdgcn_mfma_f32_16x16x32_bf16(ap, bv, o[nt], 0, 0, 0);
      }
    }
  }

  // epilogue
#pragma unroll
  for (int nt = 0; nt < 4; nt++)
#pragma unroll
    for (int r = 0; r < 4; r++) {
      const int row = q0 + wave * 16 + quad * 4 + r;
      const int col = h * 64 + nt * 16 + l15;
      AO[((long)b * 1024 + row) * 1024 + col] = (bf16_t)(o[nt][r] / l_i[r]);
    }
}

// ---------------------------------------------------------------------------
// LN1: out_bf16[row] = LN(q_f32[row] + xb_bf16[row]) * g + bt. one block/row.
__global__ __launch_bounds__(256)
void ln_res1(const float* __restrict__ xa, const bf16_t* __restrict__ xb,
             const float* __restrict__ g, const float* __restrict__ bt,
             bf16_t* __restrict__ out) {
  __shared__ float red[256];
  const int t = threadIdx.x;
  const long row = blockIdx.x;
  float v[4], s = 0.f, s2 = 0.f;
#pragma unroll
  for (int i = 0; i < 4; i++) {
    const int c = t * 4 + i;
    v[i] = xa[row * 1024 + c] + (float)xb[row * 1024 + c];
    s += v[i]; s2 += v[i] * v[i];
  }
  red[t] = s; __syncthreads();
  for (int k = 128; k; k >>= 1) { if (t < k) red[t] += red[t + k]; __syncthreads(); }
  const float mean = red[0] * (1.f / 1024.f);
  __syncthreads();
  red[t] = s2; __syncthreads();
  for (int k = 128; k; k >>= 1) { if (t < k) red[t] += red[t + k]; __syncthreads(); }
  const float var = red[0] * (1.f / 1024.f) - mean * mean;
  const float rstd = rsqrtf(var + 1e-5f);
#pragma unroll
  for (int i = 0; i < 4; i++) {
    const int c = t * 4 + i;
    out[row * 1024 + c] = (bf16_t)((v[i] - mean) * rstd * g[c] + bt[c]);
  }
}

// LN2: out_f32[row] = LN(xa_bf16[row] + xb_bf16[row]) * g + bt. one block/row.
__global__ __launch_bounds__(256)
void ln_res2(const bf16_t* __restrict__ xa, const bf16_t* __restrict__ xb,
             const float* __restrict__ g, const float* __restrict__ bt,
             float* __restrict__ out) {
  __shared__ float red[256];
  const int t = threadIdx.x;
  const long row = blockIdx.x;
  float v[4], s = 0.f, s2 = 0.f;
#pragma unroll
  for (int i = 0; i < 4; i++) {
    const int c = t * 4 + i;
    v[i] = (float)xa[row * 1024 + c] + (float)xb[row * 1024 + c];
    s += v[i]; s2 += v[i] * v[i];
  }
  red[t] = s; __syncthreads();
  for (int k = 128; k; k >>= 1) { if (t < k) red[t] += red[t + k]; __syncthreads(); }
  const float mean = red[0] * (1.f / 1024.f);
  __syncthreads();
  red[t] = s2; __syncthreads();
  for (int k = 128; k; k >>= 1) { if (t < k) red[t] += red[t + k]; __syncthreads(); }
  const float var = red[0] * (1.f / 1024.f) - mean * mean;
  const float rstd = rsqrtf(var + 1e-5f);
#pragma unroll
  for (int i = 0; i < 4; i++) {
    const int c = t * 4 + i;
    out[row * 1024 + c] = (v[i] - mean) * rstd * g[c] + bt[c];
  }
}

// ---------------------------------------------------------------------------
extern "C" void kernel_launch(void* const* d_in, const int* in_sizes, int n_in,
                              void* d_out, int out_size, void* d_ws, size_t ws_size,
                              hipStream_t stream) {
  (void)in_sizes; (void)n_in; (void)out_size; (void)ws_size;
  const float* q   = (const float*)d_in[0];
  const float* kv  = (const float*)d_in[1];
  const unsigned char* mraw = (const unsigned char*)d_in[2];
  const float* Wq = (const float*)d_in[3];
  const float* bq = (const float*)d_in[4];
  const float* Wk = (const float*)d_in[5];
  const float* bk = (const float*)d_in[6];
  const float* Wv = (const float*)d_in[7];
  const float* bv = (const float*)d_in[8];
  const float* Wo = (const float*)d_in[9];
  const float* bo = (const float*)d_in[10];
  const float* g1 = (const float*)d_in[11];
  const float* be1 = (const float*)d_in[12];
  const float* W1 = (const float*)d_in[13];
  const float* b1 = (const float*)d_in[14];
  const float* W2 = (const float*)d_in[15];
  const float* b2 = (const float*)d_in[16];
  const float* g2 = (const float*)d_in[17];
  const float* be2 = (const float*)d_in[18];
  float* out = (float*)d_out;

  char* ws = (char*)d_ws;
  size_t off = 0;
  auto alloc = [&](size_t bytes) -> char* {
    char* p = ws + off; off += (bytes + 255) & ~(size_t)255; return p;
  };
  const size_t MB16 = (size_t)8192 * 1024 * 2;   // one [8192,1024] bf16 buffer
  float*  maskf = (float*)alloc(8192 * 4);
  bf16_t* WqT = (bf16_t*)alloc((size_t)1024 * 1024 * 2);
  bf16_t* WkT = (bf16_t*)alloc((size_t)1024 * 1024 * 2);
  bf16_t* WvT = (bf16_t*)alloc((size_t)1024 * 1024 * 2);
  bf16_t* WoT = (bf16_t*)alloc((size_t)1024 * 1024 * 2);
  bf16_t* W1T = (bf16_t*)alloc((size_t)1024 * 4096 * 2);
  bf16_t* W2T = (bf16_t*)alloc((size_t)4096 * 1024 * 2);
  bf16_t* Qp = (bf16_t*)alloc(MB16);
  bf16_t* Kp = (bf16_t*)alloc(MB16);
  bf16_t* Vp = (bf16_t*)alloc(MB16);
  bf16_t* AO = (bf16_t*)alloc(MB16);
  bf16_t* X1 = (bf16_t*)alloc(MB16);
  bf16_t* TL = (bf16_t*)alloc(MB16);
  // aliases (lifetimes verified):
  bf16_t* qb  = X1;   // bf16 copy of q; dead before ln_res1 writes X1
  bf16_t* kvb = TL;   // bf16 copy of kv; dead after V projection
  bf16_t* HF  = Qp;   // [8192,4096] spans Qp..AO; all dead by FFN1
  bf16_t* OP  = Kp;   // o-proj out; Kp dead after attention
  bf16_t* F2  = WqT;  // [8192,1024] spans WqT..W1T (16MB); W2T untouched

  cvt_f32_bf16<<<8192, 256, 0, stream>>>(q,  qb,  8192 * 1024);
  cvt_f32_bf16<<<8192, 256, 0, stream>>>(kv, kvb, 8192 * 1024);
  prep_mask<<<dim3(8), dim3(256), 0, stream>>>(mraw, maskf);
  transpose_w<<<dim3(16, 16), 256, 0, stream>>>(Wq, WqT, 1024, 1024);
  transpose_w<<<dim3(16, 16), 256, 0, stream>>>(Wk, WkT, 1024, 1024);
  transpose_w<<<dim3(16, 16), 256, 0, stream>>>(Wv, WvT, 1024, 1024);
  transpose_w<<<dim3(16, 16), 256, 0, stream>>>(Wo, WoT, 1024, 1024);
  transpose_w<<<dim3(64, 16), 256, 0, stream>>>(W1, W1T, 1024, 4096);
  transpose_w<<<dim3(16, 64), 256, 0, stream>>>(W2, W2T, 4096, 1024);

  const dim3 gproj(8, 64);
  gemm_bt<<<gproj, 256, 0, stream>>>(qb,  WqT, bq, Qp, 8192, 1024, 1024, 0);
  gemm_bt<<<gproj, 256, 0, stream>>>(kvb, WkT, bk, Kp, 8192, 1024, 1024, 0);
  gemm_bt<<<gproj, 256, 0, stream>>>(kvb, WvT, bv, Vp, 8192, 1024, 1024, 0);

  attn<<<dim3(16, 16, 8), 256, 0, stream>>>(Qp, Kp, Vp, maskf, AO);

  gemm_bt<<<gproj, 256, 0, stream>>>(AO, WoT, bo, OP, 8192, 1024, 1024, 0);
  ln_res1<<<8192, 256, 0, stream>>>(q, OP, g1, be1, X1);

  gemm_bt<<<dim3(32, 64), 256, 0, stream>>>(X1, W1T, b1, HF, 8192, 4096, 1024, 1);
  gemm_bt<<<dim3(8, 64), 256, 0, stream>>>(HF, W2T, b2, F2, 8192, 1024, 4096, 0);
  ln_res2<<<8192, 256, 0, stream>>>(X1, F2, g2, be2, out);
}

// Round 3
// 681.230 us; speedup vs baseline: 1.0332x; 1.0332x over previous
//
#include <hip/hip_runtime.h>

typedef __bf16 bf16_t;
typedef bf16_t bf16x8 __attribute__((ext_vector_type(8)));
typedef bf16_t bf16x4 __attribute__((ext_vector_type(4)));
typedef float f32x4 __attribute__((ext_vector_type(4)));
typedef unsigned int u32;

typedef __attribute__((address_space(1))) unsigned as1_u32;
typedef __attribute__((address_space(3))) unsigned as3_u32;

#define LOG2E 1.4426950408889634f
#define QSCALE (0.125f * LOG2E)       // fold softmax scale + log2(e) into Qp
#define MASK2 (-10000.0f * LOG2E)     // additive mask in exp2 domain

// async global->LDS, 16B per lane, LDS dest = wave-uniform base + lane*16
__device__ __forceinline__ void gload16(const void* g, void* l) {
  __builtin_amdgcn_global_load_lds((as1_u32*)(void*)g, (as3_u32*)l, 16, 0, 0);
}

// ---------------------------------------------------------------------------
// fp32 -> bf16 bulk convert, q and kv in one launch. grid 8192, block 256,
// 8 elems/thread. Total 2 x 8M elems.
__global__ void cvt_qkv(const float* __restrict__ q, const float* __restrict__ kv,
                        bf16_t* __restrict__ qb, bf16_t* __restrict__ kvb) {
  long i = ((long)blockIdx.x * 256 + threadIdx.x) * 8;
  const float* src; bf16_t* dst;
  if (i < 8388608) { src = q + i; dst = qb + i; }
  else { src = kv + (i - 8388608); dst = kvb + (i - 8388608); }
  const float4 a = *(const float4*)src;
  const float4 b = *(const float4*)(src + 4);
  bf16x8 o;
  o[0] = (bf16_t)a.x; o[1] = (bf16_t)a.y; o[2] = (bf16_t)a.z; o[3] = (bf16_t)a.w;
  o[4] = (bf16_t)b.x; o[5] = (bf16_t)b.y; o[6] = (bf16_t)b.z; o[7] = (bf16_t)b.w;
  *(bf16x8*)dst = o;
}

// ---------------------------------------------------------------------------
// Mask prep: detect bool-bytes vs int32, build additive float mask (0 / MASK2)
// with the reference's "all-pad row -> unmask last key" fix. grid 8, block 256.
__global__ void prep_mask(const unsigned char* __restrict__ mraw,
                          float* __restrict__ maskf) {
  __shared__ int sred[256];
  const int t = threadIdx.x, b = blockIdx.x;
  // int32 0/1 values have zero bytes at offsets %4!=0; bool-bytes don't.
  int f = 0;
  for (int i = t; i < 2048; i += 256) {
    u32 v = ((const u32*)mraw)[i];
    if (v & 0xFFFFFF00u) f = 1;
  }
  sred[t] = f; __syncthreads();
  for (int s = 128; s; s >>= 1) { if (t < s) sred[t] |= sred[t + s]; __syncthreads(); }
  const int isByte = sred[0];
  __syncthreads();

  int vals[4]; int allpad = 1;
#pragma unroll
  for (int i = 0; i < 4; i++) {
    int k = t * 4 + i;
    int mv = isByte ? (int)mraw[b * 1024 + k] : ((const int*)mraw)[b * 1024 + k];
    vals[i] = (mv != 0);
    allpad &= vals[i];
  }
  sred[t] = allpad; __syncthreads();
  for (int s = 128; s; s >>= 1) { if (t < s) sred[t] &= sred[t + s]; __syncthreads(); }
  const int ap = sred[0];
#pragma unroll
  for (int i = 0; i < 4; i++) {
    int k = t * 4 + i;
    int m = vals[i];
    if (ap && k == 1023) m = 0;
    maskf[b * 1024 + k] = m ? MASK2 : 0.0f;
  }
}

// ---------------------------------------------------------------------------
// All 6 weight transposes (fp32 W[K][N] -> bf16 WT[N][K]) in one launch.
// Exact grid: 4x256 + 1024 + 1024 = 3072 blocks of 256.
struct TP { const float* s; bf16_t* d; int K; int N; };
struct TP6 { TP t[6]; };
__global__ void transpose_all(TP6 args) {
  __shared__ float tile[64][65];
  int bid = blockIdx.x, z, tx, ty;
  if (bid < 1024)      { z = bid >> 8;  int r = bid & 255;  tx = r & 15; ty = r >> 4; }
  else if (bid < 2048) { z = 4;         int r = bid - 1024; tx = r & 63; ty = r >> 6; }
  else                 { z = 5;         int r = bid - 2048; tx = r & 15; ty = r >> 4; }
  const TP a = args.t[z];
  const int t = threadIdx.x;
  const int n0 = tx * 64, k0 = ty * 64;
#pragma unroll
  for (int i = 0; i < 16; i++) {
    int e = i * 256 + t; int r = e >> 6, c = e & 63;
    tile[r][c] = a.s[(size_t)(k0 + r) * a.N + n0 + c];
  }
  __syncthreads();
#pragma unroll
  for (int i = 0; i < 16; i++) {
    int e = i * 256 + t; int r = e >> 6, c = e & 63;
    a.d[(size_t)(n0 + r) * a.K + k0 + c] = (bf16_t)tile[c][r];
  }
}

// ---------------------------------------------------------------------------
// GEMM: C[M][N] = (A[M][K] @ BT[N][K]^T + bias) * scale (+optional relu),
// bf16 in/out, fp32 accum/bias. bias_mode: 0 = bias[col], 1 = bias[row].
// 128x128 tile, BK=32, 16x16x32 MFMA, global_load_lds staging.
// grid (N/128, M/128), block 256 (4 waves, each 64x64).
__global__ __launch_bounds__(256)
void gemm_bt(const bf16_t* __restrict__ A, const bf16_t* __restrict__ BT,
             const float* __restrict__ bias, bf16_t* __restrict__ C,
             int M, int N, int K, int relu, int bias_mode, float scale) {
  __shared__ __align__(16) bf16_t As[128 * 32];
  __shared__ __align__(16) bf16_t Bs[128 * 32];
  const int tid = threadIdx.x;
  const int wave = tid >> 6, lane = tid & 63;
  const int quad = lane >> 4, l15 = lane & 15;
  const long bm = (long)blockIdx.y * 128, bn = (long)blockIdx.x * 128;
  const int wm = (wave >> 1) * 64, wn = (wave & 1) * 64;

  f32x4 acc[4][4];
#pragma unroll
  for (int i = 0; i < 4; i++)
#pragma unroll
    for (int j = 0; j < 4; j++) acc[i][j] = (f32x4){0.f, 0.f, 0.f, 0.f};

  // wave stages rows [wave*32, wave*32+32) of both tiles (2 insts of 16 rows)
  const bf16_t* ag = A + (bm + wave * 32 + (lane >> 2)) * (long)K + (lane & 3) * 8;
  const bf16_t* bg = BT + (bn + wave * 32 + (lane >> 2)) * (long)K + (lane & 3) * 8;
  bf16_t* as_dst = &As[wave * 1024];
  bf16_t* bs_dst = &Bs[wave * 1024];

  for (int k0 = 0; k0 < K; k0 += 32) {
    gload16(ag + k0, as_dst);
    gload16(ag + k0 + (long)16 * K, as_dst + 512);
    gload16(bg + k0, bs_dst);
    gload16(bg + k0 + (long)16 * K, bs_dst + 512);
    __syncthreads();   // drains vmcnt (global_load_lds) + lgkm

    bf16x8 af[4], bf[4];
#pragma unroll
    for (int i = 0; i < 4; i++)
      af[i] = *(const bf16x8*)&As[(wm + i * 16 + l15) * 32 + quad * 8];
#pragma unroll
    for (int i = 0; i < 4; i++)
      bf[i] = *(const bf16x8*)&Bs[(wn + i * 16 + l15) * 32 + quad * 8];
#pragma unroll
    for (int mi = 0; mi < 4; mi++)
#pragma unroll
      for (int ni = 0; ni < 4; ni++)
        acc[mi][ni] = __builtin_amdgcn_mfma_f32_16x16x32_bf16(af[mi], bf[ni], acc[mi][ni], 0, 0, 0);
    __syncthreads();
  }

  // epilogue: C/D layout col=lane&15, row=quad*4+reg (m89-verified)
#pragma unroll
  for (int mi = 0; mi < 4; mi++) {
#pragma unroll
    for (int ni = 0; ni < 4; ni++) {
      const long col = bn + wn + ni * 16 + l15;
      const float bc = bias_mode ? 0.f : bias[col];
#pragma unroll
      for (int r = 0; r < 4; r++) {
        const long row = bm + wm + mi * 16 + quad * 4 + r;
        const float bb = bias_mode ? bias[row] : bc;
        float v = (acc[mi][ni][r] + bb) * scale;
        if (relu) v = v > 0.f ? v : 0.f;
        C[row * N + col] = (bf16_t)v;
      }
    }
  }
}

// ---------------------------------------------------------------------------
// Flash attention. grid (Lq/64, H, B), block 256 (4 waves). Wave owns 16
// q-rows. Q pre-scaled by QSCALE (exp2-domain softmax, additive mask).
// Q/K/Vt tiles XOR-swizzled on 16B blocks by (row&7): conflict-free b128
// frag reads. Vt = per-head transposed V ([h*64+hd][b*1024+tok], stride 8192)
// so PV B-frags are vector loads. P round-trips per-wave LDS (m120).
__global__ __launch_bounds__(256)
void attn(const bf16_t* __restrict__ Q, const bf16_t* __restrict__ Kp,
          const bf16_t* __restrict__ Vt, const float* __restrict__ maskf,
          bf16_t* __restrict__ AO) {
  __shared__ __align__(16) bf16_t Qs[64 * 64];
  __shared__ __align__(16) bf16_t Ks[64 * 64];
  __shared__ __align__(16) bf16_t Vts[64 * 64];
  __shared__ __align__(16) bf16_t Ps[4][16 * 64];
  __shared__ float msk[64];

  const int tid = threadIdx.x;
  const int wave = tid >> 6, lane = tid & 63;
  const int quad = lane >> 4, l15 = lane & 15;
  const int q0 = blockIdx.x * 64;
  const int h = blockIdx.y;
  const int b = blockIdx.z;

  const long base_q = ((long)b * 1024 + q0) * 1024 + h * 64;
  const long base_k = (long)b * 1024 * 1024 + h * 64;
  const long base_v = (long)h * 64 * 8192 + b * 1024;   // Vt row stride 8192

  // Q tile (swizzled): 512 16B chunks
#pragma unroll
  for (int i = 0; i < 2; i++) {
    int e = i * 256 + tid; int r = e >> 3, blk = e & 7;
    const int4 v = *(const int4*)(Q + base_q + (long)r * 1024 + blk * 8);
    *(int4*)&Qs[r * 64 + ((blk ^ (r & 7)) * 8)] = v;
  }
  __syncthreads();

  // loop-invariant Q frags
  bf16x8 aq[2];
#pragma unroll
  for (int ks = 0; ks < 2; ks++) {
    int row = wave * 16 + l15;
    aq[ks] = *(const bf16x8*)&Qs[row * 64 + (((ks * 4 + quad) ^ (row & 7)) * 8)];
  }

  float m_i[4], l_i[4];
  f32x4 o[4];
#pragma unroll
  for (int r = 0; r < 4; r++) { m_i[r] = -1e30f; l_i[r] = 0.f; }
#pragma unroll
  for (int nt = 0; nt < 4; nt++) o[nt] = (f32x4){0.f, 0.f, 0.f, 0.f};

  bf16_t* Pw = &Ps[wave][0];

  for (int kt = 0; kt < 16; kt++) {
    const int k0 = kt * 64;
    __syncthreads();   // prior-iter tile reads complete
    // K tile (swizzled, via regs): row = key, 64 d-contiguous
#pragma unroll
    for (int i = 0; i < 2; i++) {
      int e = i * 256 + tid; int r = e >> 3, blk = e & 7;
      const int4 v = *(const int4*)(Kp + base_k + (long)(k0 + r) * 1024 + blk * 8);
      *(int4*)&Ks[r * 64 + ((blk ^ (r & 7)) * 8)] = v;
    }
    // Vt tile (swizzled): row = hd, 64 key-contiguous
#pragma unroll
    for (int i = 0; i < 2; i++) {
      int e = i * 256 + tid; int r = e >> 3, blk = e & 7;
      const int4 v = *(const int4*)(Vt + base_v + (long)r * 8192 + k0 + blk * 8);
      *(int4*)&Vts[r * 64 + ((blk ^ (r & 7)) * 8)] = v;
    }
    if (tid < 64) msk[tid] = maskf[b * 1024 + k0 + tid];
    __syncthreads();

    // S = Q K^T (scores already in exp2 domain via QSCALE)
    f32x4 sc[4];
#pragma unroll
    for (int nt = 0; nt < 4; nt++) {
      f32x4 s = (f32x4){0.f, 0.f, 0.f, 0.f};
#pragma unroll
      for (int ks = 0; ks < 2; ks++) {
        int krow = nt * 16 + l15;
        bf16x8 bk = *(const bf16x8*)&Ks[krow * 64 + (((ks * 4 + quad) ^ (krow & 7)) * 8)];
        s = __builtin_amdgcn_mfma_f32_16x16x32_bf16(aq[ks], bk, s, 0, 0, 0);
      }
      sc[nt] = s;
    }

    float mskv[4];
#pragma unroll
    for (int nt = 0; nt < 4; nt++) mskv[nt] = msk[nt * 16 + l15];

    // online softmax, exp2 domain (row = quad*4+r, col = nt*16+l15)
#pragma unroll
    for (int r = 0; r < 4; r++) {
      float mx = -1e30f;
#pragma unroll
      for (int nt = 0; nt < 4; nt++) {
        float s = sc[nt][r] + mskv[nt];
        sc[nt][r] = s;
        mx = fmaxf(mx, s);
      }
      mx = fmaxf(mx, __shfl_xor(mx, 1));
      mx = fmaxf(mx, __shfl_xor(mx, 2));
      mx = fmaxf(mx, __shfl_xor(mx, 4));
      mx = fmaxf(mx, __shfl_xor(mx, 8));
      const float mnew = fmaxf(m_i[r], mx);
      const float alpha = exp2f(m_i[r] - mnew);
      float ps = 0.f;
#pragma unroll
      for (int nt = 0; nt < 4; nt++) {
        float p = exp2f(sc[nt][r] - mnew);
        sc[nt][r] = p;
        ps += p;
      }
      ps += __shfl_xor(ps, 1); ps += __shfl_xor(ps, 2);
      ps += __shfl_xor(ps, 4); ps += __shfl_xor(ps, 8);
      l_i[r] = l_i[r] * alpha + ps;
      m_i[r] = mnew;
#pragma unroll
      for (int nt = 0; nt < 4; nt++) o[nt][r] *= alpha;
    }

    // P (bf16) -> per-wave LDS, swizzled; same-wave read back (no barrier)
#pragma unroll
    for (int nt = 0; nt < 4; nt++)
#pragma unroll
      for (int r = 0; r < 4; r++) {
        int row = quad * 4 + r;
        int col = nt * 16 + l15;
        Pw[row * 64 + (((col >> 3) ^ (row & 7)) * 8) + (col & 7)] = (bf16_t)sc[nt][r];
      }

    // O += P V : B-frag rows are Vt rows (hd), vector b128 reads
#pragma unroll
    for (int ks = 0; ks < 2; ks++) {
      bf16x8 ap = *(const bf16x8*)&Pw[l15 * 64 + (((ks * 4 + quad) ^ (l15 & 7)) * 8)];
#pragma unroll
      for (int nt = 0; nt < 4; nt++) {
        int vrow = nt * 16 + l15;
        bf16x8 bv = *(const bf16x8*)&Vts[vrow * 64 + (((ks * 4 + quad) ^ (vrow & 7)) * 8)];
        o[nt] = __builtin_amdgcn_mfma_f32_16x16x32_bf16(ap, bv, o[nt], 0, 0, 0);
      }
    }
  }

  // epilogue
#pragma unroll
  for (int r = 0; r < 4; r++) {
    const float rinv = 1.0f / l_i[r];
    const int row = q0 + wave * 16 + quad * 4 + r;
#pragma unroll
    for (int nt = 0; nt < 4; nt++) {
      const int col = h * 64 + nt * 16 + l15;
      AO[((long)b * 1024 + row) * 1024 + col] = (bf16_t)(o[nt][r] * rinv);
    }
  }
}

// ---------------------------------------------------------------------------
// LN1: out_bf16[row] = LN(q_f32[row] + xb_bf16[row]) * g + bt. one block/row.
// shfl-based reduction (6 shfl x2 + one 4-wave LDS combine).
__global__ __launch_bounds__(256)
void ln_res1(const float* __restrict__ xa, const bf16_t* __restrict__ xb,
             const float* __restrict__ g, const float* __restrict__ bt,
             bf16_t* __restrict__ out) {
  __shared__ float sw[8];
  const int t = threadIdx.x, w = t >> 6;
  const long row = blockIdx.x;
  const float4 a = *(const float4*)(xa + row * 1024 + t * 4);
  const bf16x4 bq = *(const bf16x4*)(xb + row * 1024 + t * 4);
  float v[4] = {a.x + (float)bq[0], a.y + (float)bq[1],
                a.z + (float)bq[2], a.w + (float)bq[3]};
  float s = v[0] + v[1] + v[2] + v[3];
  float s2 = v[0]*v[0] + v[1]*v[1] + v[2]*v[2] + v[3]*v[3];
#pragma unroll
  for (int off = 1; off < 64; off <<= 1) {
    s += __shfl_xor(s, off); s2 += __shfl_xor(s2, off);
  }
  if ((t & 63) == 0) { sw[w] = s; sw[4 + w] = s2; }
  __syncthreads();
  s = sw[0] + sw[1] + sw[2] + sw[3];
  s2 = sw[4] + sw[5] + sw[6] + sw[7];
  const float mean = s * (1.f / 1024.f);
  const float var = s2 * (1.f / 1024.f) - mean * mean;
  const float rstd = rsqrtf(var + 1e-5f);
  bf16x4 o;
#pragma unroll
  for (int i = 0; i < 4; i++) {
    const int c = t * 4 + i;
    o[i] = (bf16_t)((v[i] - mean) * rstd * g[c] + bt[c]);
  }
  *(bf16x4*)(out + row * 1024 + t * 4) = o;
}

// LN2: out_f32[row] = LN(xa_bf16[row] + xb_bf16[row]) * g + bt. one block/row.
__global__ __launch_bounds__(256)
void ln_res2(const bf16_t* __restrict__ xa, const bf16_t* __restrict__ xb,
             const float* __restrict__ g, const float* __restrict__ bt,
             float* __restrict__ out) {
  __shared__ float sw[8];
  const int t = threadIdx.x, w = t >> 6;
  const long row = blockIdx.x;
  const bf16x4 aq = *(const bf16x4*)(xa + row * 1024 + t * 4);
  const bf16x4 bq = *(const bf16x4*)(xb + row * 1024 + t * 4);
  float v[4];
#pragma unroll
  for (int i = 0; i < 4; i++) v[i] = (float)aq[i] + (float)bq[i];
  float s = v[0] + v[1] + v[2] + v[3];
  float s2 = v[0]*v[0] + v[1]*v[1] + v[2]*v[2] + v[3]*v[3];
#pragma unroll
  for (int off = 1; off < 64; off <<= 1) {
    s += __shfl_xor(s, off); s2 += __shfl_xor(s2, off);
  }
  if ((t & 63) == 0) { sw[w] = s; sw[4 + w] = s2; }
  __syncthreads();
  s = sw[0] + sw[1] + sw[2] + sw[3];
  s2 = sw[4] + sw[5] + sw[6] + sw[7];
  const float mean = s * (1.f / 1024.f);
  const float var = s2 * (1.f / 1024.f) - mean * mean;
  const float rstd = rsqrtf(var + 1e-5f);
  float4 o;
  o.x = (v[0] - mean) * rstd * g[t*4+0] + bt[t*4+0];
  o.y = (v[1] - mean) * rstd * g[t*4+1] + bt[t*4+1];
  o.z = (v[2] - mean) * rstd * g[t*4+2] + bt[t*4+2];
  o.w = (v[3] - mean) * rstd * g[t*4+3] + bt[t*4+3];
  *(float4*)(out + row * 1024 + t * 4) = o;
}

// ---------------------------------------------------------------------------
extern "C" void kernel_launch(void* const* d_in, const int* in_sizes, int n_in,
                              void* d_out, int out_size, void* d_ws, size_t ws_size,
                              hipStream_t stream) {
  (void)in_sizes; (void)n_in; (void)out_size; (void)ws_size;
  const float* q   = (const float*)d_in[0];
  const float* kv  = (const float*)d_in[1];
  const unsigned char* mraw = (const unsigned char*)d_in[2];
  const float* Wq = (const float*)d_in[3];
  const float* bq = (const float*)d_in[4];
  const float* Wk = (const float*)d_in[5];
  const float* bk = (const float*)d_in[6];
  const float* Wv = (const float*)d_in[7];
  const float* bv = (const float*)d_in[8];
  const float* Wo = (const float*)d_in[9];
  const float* bo = (const float*)d_in[10];
  const float* g1 = (const float*)d_in[11];
  const float* be1 = (const float*)d_in[12];
  const float* W1 = (const float*)d_in[13];
  const float* b1 = (const float*)d_in[14];
  const float* W2 = (const float*)d_in[15];
  const float* b2 = (const float*)d_in[16];
  const float* g2 = (const float*)d_in[17];
  const float* be2 = (const float*)d_in[18];
  float* out = (float*)d_out;

  char* ws = (char*)d_ws;
  size_t off = 0;
  auto alloc = [&](size_t bytes) -> char* {
    char* p = ws + off; off += (bytes + 255) & ~(size_t)255; return p;
  };
  const size_t MB16 = (size_t)8192 * 1024 * 2;   // one [8192,1024] bf16 buffer
  float*  maskf = (float*)alloc(8192 * 4);
  bf16_t* WqT = (bf16_t*)alloc((size_t)1024 * 1024 * 2);
  bf16_t* WkT = (bf16_t*)alloc((size_t)1024 * 1024 * 2);
  bf16_t* WvT = (bf16_t*)alloc((size_t)1024 * 1024 * 2);
  bf16_t* WoT = (bf16_t*)alloc((size_t)1024 * 1024 * 2);
  bf16_t* W1T = (bf16_t*)alloc((size_t)1024 * 4096 * 2);
  bf16_t* W2T = (bf16_t*)alloc((size_t)4096 * 1024 * 2);
  bf16_t* Qp = (bf16_t*)alloc(MB16);
  bf16_t* Kp = (bf16_t*)alloc(MB16);
  bf16_t* VT = (bf16_t*)alloc(MB16);   // [1024 (h*64+hd)][8192 (b*1024+tok)]
  bf16_t* AO = (bf16_t*)alloc(MB16);
  bf16_t* X1 = (bf16_t*)alloc(MB16);
  bf16_t* TL = (bf16_t*)alloc(MB16);
  // aliases (lifetimes verified):
  bf16_t* qb  = X1;   // bf16 q; dead before ln_res1 writes X1
  bf16_t* kvb = TL;   // bf16 kv; dead after K/V projections
  bf16_t* HF  = Qp;   // [8192,4096] spans Qp..AO; all dead by FFN1
  bf16_t* OP  = Kp;   // o-proj out; Kp dead after attention
  bf16_t* F2  = WqT;  // [8192,1024] spans WqT..W1T (16MB); W2T untouched

  cvt_qkv<<<8192, 256, 0, stream>>>(q, kv, qb, kvb);
  prep_mask<<<8, 256, 0, stream>>>(mraw, maskf);
  TP6 tp = {{ {Wq, WqT, 1024, 1024}, {Wk, WkT, 1024, 1024},
              {Wv, WvT, 1024, 1024}, {Wo, WoT, 1024, 1024},
              {W1, W1T, 1024, 4096}, {W2, W2T, 4096, 1024} }};
  transpose_all<<<3072, 256, 0, stream>>>(tp);

  const dim3 gproj(8, 64);
  // Qp scaled into exp2 score domain
  gemm_bt<<<gproj, 256, 0, stream>>>(qb,  WqT, bq, Qp, 8192, 1024, 1024, 0, 0, QSCALE);
  gemm_bt<<<gproj, 256, 0, stream>>>(kvb, WkT, bk, Kp, 8192, 1024, 1024, 0, 0, 1.f);
  // V projection computed transposed: VT[n][m] = (kv@Wv+bv)^T  (swap operands)
  gemm_bt<<<dim3(64, 8), 256, 0, stream>>>(WvT, kvb, bv, VT, 1024, 8192, 1024, 0, 1, 1.f);

  attn<<<dim3(16, 16, 8), 256, 0, stream>>>(Qp, Kp, VT, maskf, AO);

  gemm_bt<<<gproj, 256, 0, stream>>>(AO, WoT, bo, OP, 8192, 1024, 1024, 0, 0, 1.f);
  ln_res1<<<8192, 256, 0, stream>>>(q, OP, g1, be1, X1);

  gemm_bt<<<dim3(32, 64), 256, 0, stream>>>(X1, W1T, b1, HF, 8192, 4096, 1024, 1, 0, 1.f);
  gemm_bt<<<dim3(8, 64), 256, 0, stream>>>(HF, W2T, b2, F2, 8192, 1024, 4096, 0, 0, 1.f);
  ln_res2<<<8192, 256, 0, stream>>>(X1, F2, g2, be2, out);
}